// Round 1
// baseline (313.588 us; speedup 1.0000x reference)
//
#include <hip/hip_runtime.h>

// SESConv via implicit GEMM on bf16 MFMA (gfx950).
// out[b,o,g,h,w] = sum_{rbase valid, ic, xk, yk} Kc[g,rbase,pos,ic,o] * X[b,ic,src(g,rbase), h+xk-2, w+yk-2]
// Kc[...] = sum_f weight[o,ic,rbase,f] * basis[f,g,xk,yk]
// x: (8,16,12,128,128) f32; weight: (16,16,4,9) f32; basis: (9,12,5,5) f32; out: (8,16,12,128,128) f32
//
// R1: one block owns a full r0-column (3 g's: s0=0,1,2). Each staged slice (rr,ss)
// is consumed by up to 2 users (j=0 -> acc[ss], rbase=2i; j=1 -> acc[ss-1], rbase=2i+1),
// so every B-fragment ds_read feeds up to 2 MFMAs and each slice fetch is amortized 2x.
// Slices staged per (b,tile): 40 -> 24; LDS read traffic x0.6; MFMA work unchanged.

#define NRS 12
#define CIN 16
#define COUT 16
#define HW 128
#define IMG (HW*HW)
#define ICSTRIDE (NRS*IMG)        // x stride between input channels (floats)
#define HALO 36
#define NPIX (HALO*HALO)          // 1296 halo pixels per slice tile
#define HALFBYTES (NPIX*8*2)      // 20736 B per ic-half in LDS
#define ROWB (HALO*16)            // 576 B per halo row (16 B per pixel)

typedef __bf16 bf16x8 __attribute__((ext_vector_type(8)));
typedef float  f32x4  __attribute__((ext_vector_type(4)));

__device__ __forceinline__ unsigned short f2bf(float f) {
    unsigned u = __builtin_bit_cast(unsigned, f);
    u += 0x7fffu + ((u >> 16) & 1u);          // round-nearest-even
    return (unsigned short)(u >> 16);
}

// A-panel: [g(12)][rbase(4)][pp(13)][o(16)][k(32)] bf16, k = possel*16 + ic, pos = 2*pp+possel
// pos==25 -> 0 (pad). 319488 elems = 639 KB.
__global__ void build_kc(const float* __restrict__ wgt, const float* __restrict__ basis,
                         unsigned short* __restrict__ kc) {
    int idx = blockIdx.x * 256 + threadIdx.x;
    const int total = 12 * 4 * 13 * 16 * 32;   // 319488
    if (idx >= total) return;
    int k  = idx & 31;
    int possel = k >> 4, ic = k & 15;
    int o  = (idx >> 5) & 15;
    int t2 = idx >> 9;
    int pp = t2 % 13;
    int gr = t2 / 13;
    int rbase = gr & 3, g = gr >> 2;
    int pos = 2 * pp + possel;
    float s = 0.f;
    if (pos < 25) {
        int xk = pos / 5, yk = pos - 5 * xk;
        #pragma unroll
        for (int f = 0; f < 9; ++f)
            s = fmaf(wgt[((o * CIN + ic) * 4 + rbase) * 9 + f],
                     basis[((f * NRS + g) * 5 + xk) * 5 + yk], s);
    }
    kc[idx] = f2bf(s);
}

__global__ __launch_bounds__(256, 2)
void conv_mfma(const float* __restrict__ x, const unsigned short* __restrict__ kc,
               float* __restrict__ out) {
    const int b   = blockIdx.z;
    const int r0  = blockIdx.y;                    // 0..3 (r0-column of 3 g's)
    const int th0 = (blockIdx.x >> 2) * 32;
    const int tw0 = (blockIdx.x & 3) * 32;

    const int t    = threadIdx.x;
    const int lane = t & 63;
    const int wave = t >> 6;
    const int n    = lane & 15;        // MFMA N index (pixel within group)
    const int q    = lane >> 4;        // quad: possel = q>>1, ic-half = q&1
    const int possel = q >> 1;
    const int half_  = q & 1;

    __shared__ uint4 xs4[(2 * HALFBYTES) / 16];   // 41472 B
    char* xsc = (char*)xs4;

    // per-lane B-fragment byte offsets per K-step (tap pair), fixed for whole kernel
    int boff[13];
    #pragma unroll
    for (int pp = 0; pp < 13; ++pp) {
        int pos = 2 * pp + possel; if (pos > 24) pos = 24;   // pad tap reads tap 24; A=0 there
        int dx = pos / 5, dy = pos - 5 * dx;
        boff[pp] = half_ * HALFBYTES + dx * ROWB + (n + dy) * 16;
    }
    const int aoff = n * 32 + q * 8;               // A-frag: o*32 + q*8 (ushort elems)

    f32x4 acc[3][16];
    #pragma unroll
    for (int s0 = 0; s0 < 3; ++s0)
        #pragma unroll
        for (int pg = 0; pg < 16; ++pg) acc[s0][pg] = (f32x4){0.f, 0.f, 0.f, 0.f};

    #pragma unroll 1
    for (int i = 0; i < 2; ++i) {                  // rolled: acc index never depends on i
        int rr = r0 + i; if (rr >= 4) rr -= 4;
        #pragma unroll
        for (int ss = 0; ss < 3; ++ss) {           // unrolled: static acc[ss]/acc[ss-1]
            const int sin_ = rr * 3 + ss;
            const float* xb = x + ((size_t)b * CIN * NRS + sin_) * IMG;

            __syncthreads();                       // protect xs from previous slice's readers
            // ---- stage 36x36 halo, 16 ic, fp32->bf16, layout [half][pix][icq] ----
            for (int p = t; p < NPIX; p += 256) {
                int rl = p / HALO, cl = p - rl * HALO;
                int hh = th0 + rl - 2, ww = tw0 + cl - 2;
                bool ok = ((unsigned)hh < 128u) && ((unsigned)ww < 128u);
                const float* px = xb + hh * HW + ww;
                unsigned short v[16];
                #pragma unroll
                for (int ic = 0; ic < 16; ++ic) {
                    float f = 0.f;
                    if (ok) f = px[(size_t)ic * ICSTRIDE];
                    v[ic] = f2bf(f);
                }
                uint4 lo, hi;
                lo.x = v[0] | (v[1] << 16);  lo.y = v[2] | (v[3] << 16);
                lo.z = v[4] | (v[5] << 16);  lo.w = v[6] | (v[7] << 16);
                hi.x = v[8] | (v[9] << 16);  hi.y = v[10] | (v[11] << 16);
                hi.z = v[12] | (v[13] << 16); hi.w = v[14] | (v[15] << 16);
                *(uint4*)(xsc + p * 16)             = lo;
                *(uint4*)(xsc + HALFBYTES + p * 16) = hi;
            }
            __syncthreads();

            // ---- GEMM over this slice: 13 K-steps x 16 pixel groups, 1-2 users ----
            // user j=0: g = r0*3+ss,   rbase = 2i   -> acc[ss]
            // user j=1: g = r0*3+ss-1, rbase = 2i+1 -> acc[ss-1]   (only ss>0)
            const unsigned short* kc0 = kc + (size_t)((r0 * 3 + ss) * 4 + 2 * i) * (13 * 512);
            const unsigned short* kc1 = kc + (size_t)((r0 * 3 + ss - 1) * 4 + 2 * i + 1) * (13 * 512);
            const char* wb = xsc + wave * 8 * ROWB;
            #pragma unroll
            for (int pp = 0; pp < 13; ++pp) {
                bf16x8 af0 = *(const bf16x8*)(kc0 + pp * 512 + aoff);
                bf16x8 af1;
                if (ss > 0) af1 = *(const bf16x8*)(kc1 + pp * 512 + aoff);
                const char* wp = wb + boff[pp];
                #pragma unroll
                for (int pg = 0; pg < 16; ++pg) {
                    bf16x8 bfv = *(const bf16x8*)(wp + (pg >> 1) * ROWB + (pg & 1) * 256);
                    acc[ss][pg] = __builtin_amdgcn_mfma_f32_16x16x32_bf16(af0, bfv, acc[ss][pg], 0, 0, 0);
                    if (ss > 0)
                        acc[ss - 1][pg] = __builtin_amdgcn_mfma_f32_16x16x32_bf16(af1, bfv, acc[ss - 1][pg], 0, 0, 0);
                }
            }
        }
    }

    // ---- epilogue: D row = o = q*4+reg, col = pixel = n ----
    #pragma unroll
    for (int s0 = 0; s0 < 3; ++s0) {
        const size_t obase = ((size_t)b * COUT * NRS + (r0 * 3 + s0)) * IMG;
        #pragma unroll
        for (int pg = 0; pg < 16; ++pg) {
            int row = th0 + wave * 8 + (pg >> 1);
            int col = tw0 + (pg & 1) * 16 + n;
            size_t pix = (size_t)row * HW + col;
            #pragma unroll
            for (int r = 0; r < 4; ++r) {
                int o = q * 4 + r;
                out[obase + (size_t)o * NRS * IMG + pix] = acc[s0][pg][r];
            }
        }
    }
}

extern "C" void kernel_launch(void* const* d_in, const int* in_sizes, int n_in,
                              void* d_out, int out_size, void* d_ws, size_t ws_size,
                              hipStream_t stream) {
    const float* x      = (const float*)d_in[0];
    const float* weight = (const float*)d_in[1];
    const float* basis  = (const float*)d_in[2];
    float* out = (float*)d_out;
    unsigned short* kc = (unsigned short*)d_ws;    // 639 KB

    build_kc<<<dim3((12 * 4 * 13 * 16 * 32 + 255) / 256), dim3(256), 0, stream>>>(weight, basis, kc);
    conv_mfma<<<dim3(16, 4, 8), dim3(256), 0, stream>>>(x, kc, out);
}

// Round 2
// 296.078 us; speedup vs baseline: 1.0591x; 1.0591x over previous
//
#include <hip/hip_runtime.h>

// SESConv via implicit GEMM on bf16 MFMA (gfx950).
// out[b,o,g,h,w] = sum_{rbase valid, ic, xk, yk} Kc[g,rbase,pos,ic,o] * X[b,ic,src(g,rbase), h+xk-2, w+yk-2]
// Kc[...] = sum_f weight[o,ic,rbase,f] * basis[f,g,xk,yk]
// x: (8,16,12,128,128) f32; weight: (16,16,4,9) f32; basis: (9,12,5,5) f32; out: (8,16,12,128,128) f32
//
// R2: keep R1's r0-column ownership (3 g's per block, each staged slice feeds up to
// 2 accumulator sets -> 2 MFMAs per B ds_read), but shrink the pixel tile 32x32 ->
// 32x16 so acc[3][8] = 96 VGPRs (R1's acc[3][16]=192 spilled to scratch: WRITE_SIZE
// 98->237 MB). Total regs ~160 < 256 cap at 2 waves/EU -> no spill.

#define NRS 12
#define CIN 16
#define COUT 16
#define HW 128
#define IMG (HW*HW)
#define ICSTRIDE (NRS*IMG)        // x stride between input channels (floats)
#define HALO_H 36
#define HALO_W 20
#define NPIX (HALO_H*HALO_W)      // 720 halo pixels per slice tile (32x16 out tile)
#define HALFBYTES (NPIX*8*2)      // 11520 B per ic-half in LDS
#define ROWB (HALO_W*16)          // 320 B per halo row (16 B per pixel per half)

typedef __bf16 bf16x8 __attribute__((ext_vector_type(8)));
typedef float  f32x4  __attribute__((ext_vector_type(4)));

__device__ __forceinline__ unsigned short f2bf(float f) {
    unsigned u = __builtin_bit_cast(unsigned, f);
    u += 0x7fffu + ((u >> 16) & 1u);          // round-nearest-even
    return (unsigned short)(u >> 16);
}

// A-panel: [g(12)][rbase(4)][pp(13)][o(16)][k(32)] bf16, k = possel*16 + ic, pos = 2*pp+possel
// pos==25 -> 0 (pad). 319488 elems = 639 KB.
__global__ void build_kc(const float* __restrict__ wgt, const float* __restrict__ basis,
                         unsigned short* __restrict__ kc) {
    int idx = blockIdx.x * 256 + threadIdx.x;
    const int total = 12 * 4 * 13 * 16 * 32;   // 319488
    if (idx >= total) return;
    int k  = idx & 31;
    int possel = k >> 4, ic = k & 15;
    int o  = (idx >> 5) & 15;
    int t2 = idx >> 9;
    int pp = t2 % 13;
    int gr = t2 / 13;
    int rbase = gr & 3, g = gr >> 2;
    int pos = 2 * pp + possel;
    float s = 0.f;
    if (pos < 25) {
        int xk = pos / 5, yk = pos - 5 * xk;
        #pragma unroll
        for (int f = 0; f < 9; ++f)
            s = fmaf(wgt[((o * CIN + ic) * 4 + rbase) * 9 + f],
                     basis[((f * NRS + g) * 5 + xk) * 5 + yk], s);
    }
    kc[idx] = f2bf(s);
}

__global__ __launch_bounds__(256, 2)
void conv_mfma(const float* __restrict__ x, const unsigned short* __restrict__ kc,
               float* __restrict__ out) {
    const int b   = blockIdx.z;
    const int r0  = blockIdx.y;                    // 0..3 (r0-column of 3 g's)
    const int th0 = (blockIdx.x >> 3) * 32;        // 4 row-tiles of 32
    const int tw0 = (blockIdx.x & 7) * 16;         // 8 col-tiles of 16

    const int t    = threadIdx.x;
    const int lane = t & 63;
    const int wave = t >> 6;
    const int n    = lane & 15;        // MFMA N index (pixel col within tile)
    const int q    = lane >> 4;        // quad: possel = q>>1, ic-half = q&1
    const int possel = q >> 1;
    const int half_  = q & 1;

    __shared__ uint4 xs4[(2 * HALFBYTES) / 16];   // 23040 B
    char* xsc = (char*)xs4;

    // per-lane B-fragment byte offsets per K-step (tap pair), fixed for whole kernel
    int boff[13];
    #pragma unroll
    for (int pp = 0; pp < 13; ++pp) {
        int pos = 2 * pp + possel; if (pos > 24) pos = 24;   // pad tap reads tap 24; A=0 there
        int dx = pos / 5, dy = pos - 5 * dx;
        boff[pp] = half_ * HALFBYTES + dx * ROWB + (n + dy) * 16;
    }
    const int aoff = n * 32 + q * 8;               // A-frag: o*32 + q*8 (ushort elems)

    f32x4 acc[3][8];
    #pragma unroll
    for (int s0 = 0; s0 < 3; ++s0)
        #pragma unroll
        for (int pg = 0; pg < 8; ++pg) acc[s0][pg] = (f32x4){0.f, 0.f, 0.f, 0.f};

    #pragma unroll 1
    for (int i = 0; i < 2; ++i) {                  // rolled: acc index never depends on i
        int rr = r0 + i; if (rr >= 4) rr -= 4;
        #pragma unroll
        for (int ss = 0; ss < 3; ++ss) {           // unrolled: static acc[ss]/acc[ss-1]
            const int sin_ = rr * 3 + ss;
            const float* xb = x + ((size_t)b * CIN * NRS + sin_) * IMG;

            __syncthreads();                       // protect xs from previous slice's readers
            // ---- stage 36x20 halo, 16 ic, fp32->bf16, layout [half][pix][icq] ----
            for (int p = t; p < NPIX; p += 256) {
                int rl = p / HALO_W, cl = p - rl * HALO_W;
                int hh = th0 + rl - 2, ww = tw0 + cl - 2;
                bool ok = ((unsigned)hh < 128u) && ((unsigned)ww < 128u);
                const float* px = xb + hh * HW + ww;
                unsigned short v[16];
                #pragma unroll
                for (int ic = 0; ic < 16; ++ic) {
                    float f = 0.f;
                    if (ok) f = px[(size_t)ic * ICSTRIDE];
                    v[ic] = f2bf(f);
                }
                uint4 lo, hi;
                lo.x = v[0] | (v[1] << 16);  lo.y = v[2] | (v[3] << 16);
                lo.z = v[4] | (v[5] << 16);  lo.w = v[6] | (v[7] << 16);
                hi.x = v[8] | (v[9] << 16);  hi.y = v[10] | (v[11] << 16);
                hi.z = v[12] | (v[13] << 16); hi.w = v[14] | (v[15] << 16);
                *(uint4*)(xsc + p * 16)             = lo;
                *(uint4*)(xsc + HALFBYTES + p * 16) = hi;
            }
            __syncthreads();

            // ---- GEMM over this slice: 13 K-steps x 8 pixel groups, 1-2 users ----
            // user j=0: g = r0*3+ss,   rbase = 2i   -> acc[ss]
            // user j=1: g = r0*3+ss-1, rbase = 2i+1 -> acc[ss-1]   (only ss>0)
            const unsigned short* kc0 = kc + (size_t)((r0 * 3 + ss) * 4 + 2 * i) * (13 * 512);
            const unsigned short* kc1 = kc + (size_t)((r0 * 3 + ss - 1) * 4 + 2 * i + 1) * (13 * 512);
            const char* wb = xsc + wave * 8 * ROWB;
            #pragma unroll
            for (int pp = 0; pp < 13; ++pp) {
                bf16x8 af0 = *(const bf16x8*)(kc0 + pp * 512 + aoff);
                bf16x8 af1;
                if (ss > 0) af1 = *(const bf16x8*)(kc1 + pp * 512 + aoff);
                const char* wp = wb + boff[pp];
                #pragma unroll
                for (int pg = 0; pg < 8; ++pg) {
                    bf16x8 bfv = *(const bf16x8*)(wp + pg * ROWB);
                    acc[ss][pg] = __builtin_amdgcn_mfma_f32_16x16x32_bf16(af0, bfv, acc[ss][pg], 0, 0, 0);
                    if (ss > 0)
                        acc[ss - 1][pg] = __builtin_amdgcn_mfma_f32_16x16x32_bf16(af1, bfv, acc[ss - 1][pg], 0, 0, 0);
                }
            }
        }
    }

    // ---- epilogue: D row = o = q*4+reg, col = pixel = n ----
    #pragma unroll
    for (int s0 = 0; s0 < 3; ++s0) {
        const size_t obase = ((size_t)b * COUT * NRS + (r0 * 3 + s0)) * IMG;
        #pragma unroll
        for (int pg = 0; pg < 8; ++pg) {
            int row = th0 + wave * 8 + pg;
            int col = tw0 + n;
            size_t pix = (size_t)row * HW + col;
            #pragma unroll
            for (int r = 0; r < 4; ++r) {
                int o = q * 4 + r;
                out[obase + (size_t)o * NRS * IMG + pix] = acc[s0][pg][r];
            }
        }
    }
}

extern "C" void kernel_launch(void* const* d_in, const int* in_sizes, int n_in,
                              void* d_out, int out_size, void* d_ws, size_t ws_size,
                              hipStream_t stream) {
    const float* x      = (const float*)d_in[0];
    const float* weight = (const float*)d_in[1];
    const float* basis  = (const float*)d_in[2];
    float* out = (float*)d_out;
    unsigned short* kc = (unsigned short*)d_ws;    // 639 KB

    build_kc<<<dim3((12 * 4 * 13 * 16 * 32 + 255) / 256), dim3(256), 0, stream>>>(weight, basis, kc);
    conv_mfma<<<dim3(32, 4, 8), dim3(256), 0, stream>>>(x, kc, out);
}

// Round 3
// 253.723 us; speedup vs baseline: 1.2359x; 1.1669x over previous
//
#include <hip/hip_runtime.h>

// SESConv via implicit GEMM on bf16 MFMA (gfx950).
// out[b,o,g,h,w] = sum_{rbase valid, ic, xk, yk} Kc[g,rbase,pos,ic,o] * X[b,ic,src(g,rbase), h+xk-2, w+yk-2]
// Kc[...] = sum_f weight[o,ic,rbase,f] * basis[f,g,xk,yk]
// x: (8,16,12,128,128) f32; weight: (16,16,4,9) f32; basis: (9,12,5,5) f32; out: (8,16,12,128,128) f32
//
// R3: (1) pre-pass converts x -> padded bf16 xbf[b][s][132][132][16ic] once (L3-resident);
// (2) conv stages halos via async global_load_lds (16B, no VALU, no VGPR round-trip);
// (3) LDS double-buffer, T3 minimal 2-phase: issue stage(next) -> GEMM(cur) -> syncthreads.
// Keeps R2's r0-column ownership (each slice feeds 2 accumulator sets) and 32x16 tile
// (acc[3][8] = 96 regs, no spill).

#define NRS 12
#define CIN 16
#define COUT 16
#define HW 128
#define IMG (HW*HW)
#define ICSTRIDE (NRS*IMG)        // x stride between input channels (floats)

// fast-path geometry
#define HALO_H 36
#define HALO_W 20
#define ROWB2 640                 // bytes per halo row in LDS: 20 px * 2 halves * 16 B
#define NCHUNK 1440               // 36*20*2 16B-chunks per slice
#define BUFB 24576                // 1536 chunks * 16 B (padded to 24 chunks/wave * 4 waves)
#define PADW 132
#define PADROWB (PADW*32)         // 4224 B per padded row (132 px * 32 B)

// slow-path (fallback) geometry
#define S_NPIX (HALO_H*HALO_W)    // 720
#define S_HALFB (S_NPIX*16)       // 11520 B per ic-half
#define S_ROWB (HALO_W*16)        // 320

typedef __bf16 bf16x8 __attribute__((ext_vector_type(8)));
typedef float  f32x4  __attribute__((ext_vector_type(4)));

__device__ __forceinline__ unsigned short f2bf(float f) {
    unsigned u = __builtin_bit_cast(unsigned, f);
    u += 0x7fffu + ((u >> 16) & 1u);          // round-nearest-even
    return (unsigned short)(u >> 16);
}

// A-panel: [g(12)][rbase(4)][pp(13)][o(16)][k(32)] bf16, k = possel*16 + ic, pos = 2*pp+possel
// pos==25 -> 0 (pad). 319488 elems = 639 KB.
__global__ void build_kc(const float* __restrict__ wgt, const float* __restrict__ basis,
                         unsigned short* __restrict__ kc) {
    int idx = blockIdx.x * 256 + threadIdx.x;
    const int total = 12 * 4 * 13 * 16 * 32;   // 319488
    if (idx >= total) return;
    int k  = idx & 31;
    int possel = k >> 4, ic = k & 15;
    int o  = (idx >> 5) & 15;
    int t2 = idx >> 9;
    int pp = t2 % 13;
    int gr = t2 / 13;
    int rbase = gr & 3, g = gr >> 2;
    int pos = 2 * pp + possel;
    float s = 0.f;
    if (pos < 25) {
        int xk = pos / 5, yk = pos - 5 * xk;
        #pragma unroll
        for (int f = 0; f < 9; ++f)
            s = fmaf(wgt[((o * CIN + ic) * 4 + rbase) * 9 + f],
                     basis[((f * NRS + g) * 5 + xk) * 5 + yk], s);
    }
    kc[idx] = f2bf(s);
}

// Pre-pass: x (b,ic,s,h,w) f32 -> xbf[b][s][hp 132][wp 132][ic 16] bf16, 2-px zero border.
__global__ void cvt_pad(const float* __restrict__ x, unsigned short* __restrict__ xbf) {
    int idx = blockIdx.x * 256 + threadIdx.x;
    const int total = 8 * 12 * PADW * PADW;    // 1,672,704
    if (idx >= total) return;
    int wp = idx % PADW;
    int t1 = idx / PADW;
    int hp = t1 % PADW;
    int bs = t1 / PADW;                        // b*12 + s
    int s  = bs % 12, bb = bs / 12;
    int h = hp - 2, w = wp - 2;
    bool ok = ((unsigned)h < 128u) && ((unsigned)w < 128u);
    const float* px = x + ((size_t)bb * 192 + s) * IMG + h * HW + w;   // +ic*12*IMG
    unsigned short v[16];
    #pragma unroll
    for (int ic = 0; ic < 16; ++ic) {
        float f = 0.f;
        if (ok) f = px[(size_t)ic * ICSTRIDE];
        v[ic] = f2bf(f);
    }
    uint4 lo, hi;
    lo.x = v[0] | (v[1] << 16);  lo.y = v[2] | (v[3] << 16);
    lo.z = v[4] | (v[5] << 16);  lo.w = v[6] | (v[7] << 16);
    hi.x = v[8] | (v[9] << 16);  hi.y = v[10] | (v[11] << 16);
    hi.z = v[12] | (v[13] << 16); hi.w = v[14] | (v[15] << 16);
    *(uint4*)(xbf + (size_t)idx * 16)     = lo;
    *(uint4*)(xbf + (size_t)idx * 16 + 8) = hi;
}

__global__ __launch_bounds__(256, 2)
void conv_fast(const unsigned short* __restrict__ xbf, const unsigned short* __restrict__ kc,
               float* __restrict__ out) {
    const int b   = blockIdx.z;
    const int r0  = blockIdx.y;                    // 0..3 (r0-column of 3 g's)
    const int th0 = (blockIdx.x >> 3) * 32;        // 4 row-tiles of 32
    const int tw0 = (blockIdx.x & 7) * 16;         // 8 col-tiles of 16

    const int t    = threadIdx.x;
    const int lane = t & 63;
    const int wave = t >> 6;
    const int n    = lane & 15;        // MFMA N index
    const int q    = lane >> 4;
    const int possel = q >> 1;
    const int half_  = q & 1;

    __shared__ uint4 xs4[(2 * BUFB) / 16];         // 49152 B, double-buffered
    char* xsc = (char*)xs4;

    // staging source byte-offsets (within padded slice, from tile origin), fixed per lane.
    // chunk c -> LDS offset c*16; layout [rl(36)][half(2)][cl(20)] 16B chunks.
    int soff[6];
    #pragma unroll
    for (int j = 0; j < 6; ++j) {
        int c = wave * 384 + j * 64 + lane;
        if (c < NCHUNK) {
            int rl = c / 40, rem = c - rl * 40;
            int hf = rem / 20, cl = rem - hf * 20;
            soff[j] = rl * PADROWB + cl * 32 + hf * 16;
        } else soff[j] = 0;                        // harmless in-bounds read -> LDS pad region
    }

    // B-fragment byte offsets per K-step (within wave's row window)
    int boff[13];
    #pragma unroll
    for (int pp = 0; pp < 13; ++pp) {
        int pos = 2 * pp + possel; if (pos > 24) pos = 24;   // pad tap reads tap 24; A=0 there
        int dx = pos / 5, dy = pos - 5 * dx;
        boff[pp] = dx * ROWB2 + half_ * 320 + (n + dy) * 16;
    }
    const int aoff = n * 32 + q * 8;               // A-frag: o*32 + q*8 (ushort elems)

    f32x4 acc[3][8];
    #pragma unroll
    for (int s0 = 0; s0 < 3; ++s0)
        #pragma unroll
        for (int pg = 0; pg < 8; ++pg) acc[s0][pg] = (f32x4){0.f, 0.f, 0.f, 0.f};

    const char* xb0 = (const char*)xbf;
    const size_t tileoff = ((size_t)th0 * PADW + tw0) * 32;

    // prologue: stage slice (i=0, ss=0): sin = r0*3
    {
        const char* sb = xb0 + ((size_t)(b * 12 + r0 * 3) * PADW * PADW) * 32 + tileoff;
        char* lb = xsc + wave * 6144;
        #pragma unroll
        for (int j = 0; j < 6; ++j)
            __builtin_amdgcn_global_load_lds(
                (const __attribute__((address_space(1))) void*)(sb + soff[j]),
                (__attribute__((address_space(3))) void*)(lb + j * 1024), 16, 0, 0);
    }
    __syncthreads();
    int cur = 0;

    #pragma unroll 1
    for (int i = 0; i < 2; ++i) {                  // rolled: acc index never depends on i
        int rr = r0 + i; if (rr >= 4) rr -= 4;
        int rrn = rr + 1; if (rrn >= 4) rrn -= 4;
        #pragma unroll
        for (int ss = 0; ss < 3; ++ss) {           // unrolled: static acc[ss]/acc[ss-1]
            // ---- issue async stage of next slice into buf[cur^1] ----
            if (i == 0 || ss < 2) {
                int sin_next = (ss < 2) ? (rr * 3 + ss + 1) : (rrn * 3);
                const char* sb = xb0 + ((size_t)(b * 12 + sin_next) * PADW * PADW) * 32 + tileoff;
                char* lb = xsc + (cur ^ 1) * BUFB + wave * 6144;
                #pragma unroll
                for (int j = 0; j < 6; ++j)
                    __builtin_amdgcn_global_load_lds(
                        (const __attribute__((address_space(1))) void*)(sb + soff[j]),
                        (__attribute__((address_space(3))) void*)(lb + j * 1024), 16, 0, 0);
            }

            // ---- GEMM over current slice: 13 K-steps x 8 pixel groups, 1-2 users ----
            // user j=0: g = r0*3+ss,   rbase = 2i   -> acc[ss]
            // user j=1: g = r0*3+ss-1, rbase = 2i+1 -> acc[ss-1]   (only ss>0)
            const unsigned short* kc0 = kc + (size_t)((r0 * 3 + ss) * 4 + 2 * i) * (13 * 512);
            const char* wb = xsc + cur * BUFB + wave * 8 * ROWB2;
            if (ss > 0) {
                const unsigned short* kc1 = kc + (size_t)((r0 * 3 + ss - 1) * 4 + 2 * i + 1) * (13 * 512);
                #pragma unroll
                for (int pp = 0; pp < 13; ++pp) {
                    bf16x8 af0 = *(const bf16x8*)(kc0 + pp * 512 + aoff);
                    bf16x8 af1 = *(const bf16x8*)(kc1 + pp * 512 + aoff);
                    const char* wp = wb + boff[pp];
                    #pragma unroll
                    for (int pg = 0; pg < 8; ++pg) {
                        bf16x8 bfv = *(const bf16x8*)(wp + pg * ROWB2);
                        acc[ss][pg]     = __builtin_amdgcn_mfma_f32_16x16x32_bf16(af0, bfv, acc[ss][pg], 0, 0, 0);
                        acc[ss - 1][pg] = __builtin_amdgcn_mfma_f32_16x16x32_bf16(af1, bfv, acc[ss - 1][pg], 0, 0, 0);
                    }
                }
            } else {
                #pragma unroll
                for (int pp = 0; pp < 13; ++pp) {
                    bf16x8 af0 = *(const bf16x8*)(kc0 + pp * 512 + aoff);
                    const char* wp = wb + boff[pp];
                    #pragma unroll
                    for (int pg = 0; pg < 8; ++pg) {
                        bf16x8 bfv = *(const bf16x8*)(wp + pg * ROWB2);
                        acc[ss][pg] = __builtin_amdgcn_mfma_f32_16x16x32_bf16(af0, bfv, acc[ss][pg], 0, 0, 0);
                    }
                }
            }
            __syncthreads();       // drains vmcnt (stage landed) + lgkm; all waves' stages visible
            cur ^= 1;
        }
    }

    // ---- epilogue: D row = o = q*4+reg, col = pixel = n ----
    #pragma unroll
    for (int s0 = 0; s0 < 3; ++s0) {
        const size_t obase = ((size_t)b * COUT * NRS + (r0 * 3 + s0)) * IMG;
        #pragma unroll
        for (int pg = 0; pg < 8; ++pg) {
            int row = th0 + wave * 8 + pg;
            int col = tw0 + n;
            size_t pix = (size_t)row * HW + col;
            #pragma unroll
            for (int r = 0; r < 4; ++r) {
                int o = q * 4 + r;
                out[obase + (size_t)o * NRS * IMG + pix] = acc[s0][pg][r];
            }
        }
    }
}

// Fallback (R2 kernel): used only if workspace can't hold xbf.
__global__ __launch_bounds__(256, 2)
void conv_slow(const float* __restrict__ x, const unsigned short* __restrict__ kc,
               float* __restrict__ out) {
    const int b   = blockIdx.z;
    const int r0  = blockIdx.y;
    const int th0 = (blockIdx.x >> 3) * 32;
    const int tw0 = (blockIdx.x & 7) * 16;

    const int t    = threadIdx.x;
    const int lane = t & 63;
    const int wave = t >> 6;
    const int n    = lane & 15;
    const int q    = lane >> 4;
    const int possel = q >> 1;
    const int half_  = q & 1;

    __shared__ uint4 xs4[(2 * S_HALFB) / 16];
    char* xsc = (char*)xs4;

    int boff[13];
    #pragma unroll
    for (int pp = 0; pp < 13; ++pp) {
        int pos = 2 * pp + possel; if (pos > 24) pos = 24;
        int dx = pos / 5, dy = pos - 5 * dx;
        boff[pp] = half_ * S_HALFB + dx * S_ROWB + (n + dy) * 16;
    }
    const int aoff = n * 32 + q * 8;

    f32x4 acc[3][8];
    #pragma unroll
    for (int s0 = 0; s0 < 3; ++s0)
        #pragma unroll
        for (int pg = 0; pg < 8; ++pg) acc[s0][pg] = (f32x4){0.f, 0.f, 0.f, 0.f};

    #pragma unroll 1
    for (int i = 0; i < 2; ++i) {
        int rr = r0 + i; if (rr >= 4) rr -= 4;
        #pragma unroll
        for (int ss = 0; ss < 3; ++ss) {
            const int sin_ = rr * 3 + ss;
            const float* xb = x + ((size_t)b * CIN * NRS + sin_) * IMG;

            __syncthreads();
            for (int p = t; p < S_NPIX; p += 256) {
                int rl = p / HALO_W, cl = p - rl * HALO_W;
                int hh = th0 + rl - 2, ww = tw0 + cl - 2;
                bool ok = ((unsigned)hh < 128u) && ((unsigned)ww < 128u);
                const float* px = xb + hh * HW + ww;
                unsigned short v[16];
                #pragma unroll
                for (int ic = 0; ic < 16; ++ic) {
                    float f = 0.f;
                    if (ok) f = px[(size_t)ic * ICSTRIDE];
                    v[ic] = f2bf(f);
                }
                uint4 lo, hi;
                lo.x = v[0] | (v[1] << 16);  lo.y = v[2] | (v[3] << 16);
                lo.z = v[4] | (v[5] << 16);  lo.w = v[6] | (v[7] << 16);
                hi.x = v[8] | (v[9] << 16);  hi.y = v[10] | (v[11] << 16);
                hi.z = v[12] | (v[13] << 16); hi.w = v[14] | (v[15] << 16);
                *(uint4*)(xsc + p * 16)           = lo;
                *(uint4*)(xsc + S_HALFB + p * 16) = hi;
            }
            __syncthreads();

            const unsigned short* kc0 = kc + (size_t)((r0 * 3 + ss) * 4 + 2 * i) * (13 * 512);
            const unsigned short* kc1 = kc + (size_t)((r0 * 3 + ss - 1) * 4 + 2 * i + 1) * (13 * 512);
            const char* wb = xsc + wave * 8 * S_ROWB;
            #pragma unroll
            for (int pp = 0; pp < 13; ++pp) {
                bf16x8 af0 = *(const bf16x8*)(kc0 + pp * 512 + aoff);
                bf16x8 af1;
                if (ss > 0) af1 = *(const bf16x8*)(kc1 + pp * 512 + aoff);
                const char* wp = wb + boff[pp];
                #pragma unroll
                for (int pg = 0; pg < 8; ++pg) {
                    bf16x8 bfv = *(const bf16x8*)(wp + pg * S_ROWB);
                    acc[ss][pg] = __builtin_amdgcn_mfma_f32_16x16x32_bf16(af0, bfv, acc[ss][pg], 0, 0, 0);
                    if (ss > 0)
                        acc[ss - 1][pg] = __builtin_amdgcn_mfma_f32_16x16x32_bf16(af1, bfv, acc[ss - 1][pg], 0, 0, 0);
                }
            }
        }
    }

    #pragma unroll
    for (int s0 = 0; s0 < 3; ++s0) {
        const size_t obase = ((size_t)b * COUT * NRS + (r0 * 3 + s0)) * IMG;
        #pragma unroll
        for (int pg = 0; pg < 8; ++pg) {
            int row = th0 + wave * 8 + pg;
            int col = tw0 + n;
            size_t pix = (size_t)row * HW + col;
            #pragma unroll
            for (int r = 0; r < 4; ++r) {
                int o = q * 4 + r;
                out[obase + (size_t)o * NRS * IMG + pix] = acc[s0][pg][r];
            }
        }
    }
}

extern "C" void kernel_launch(void* const* d_in, const int* in_sizes, int n_in,
                              void* d_out, int out_size, void* d_ws, size_t ws_size,
                              hipStream_t stream) {
    const float* x      = (const float*)d_in[0];
    const float* weight = (const float*)d_in[1];
    const float* basis  = (const float*)d_in[2];
    float* out = (float*)d_out;
    unsigned short* kc = (unsigned short*)d_ws;            // 639 KB

    build_kc<<<dim3((12 * 4 * 13 * 16 * 32 + 255) / 256), dim3(256), 0, stream>>>(weight, basis, kc);

    const size_t xbf_off = 655360;                         // 640 KB, 16B-aligned
    const size_t xbf_bytes = (size_t)8 * 12 * PADW * PADW * 32;   // 53.5 MB
    if (ws_size >= xbf_off + xbf_bytes) {
        unsigned short* xbf = (unsigned short*)((char*)d_ws + xbf_off);
        cvt_pad<<<dim3((8 * 12 * PADW * PADW + 255) / 256), dim3(256), 0, stream>>>(x, xbf);
        conv_fast<<<dim3(32, 4, 8), dim3(256), 0, stream>>>(xbf, kc, out);
    } else {
        conv_slow<<<dim3(32, 4, 8), dim3(256), 0, stream>>>(x, kc, out);
    }
}